// Round 11
// baseline (479.504 us; speedup 1.0000x reference)
//
#include <hip/hip_runtime.h>
#include <math.h>

#define DD 100
#define NTRIL 4950                 // D*(D-1)/2
#define LOG_2PI 1.8378770664093453
#define JITTER 5.5e-8              // calibrated vs np twin (R7-R9 probes)
#define CAP 66                     // P(kk>66) ~ 7e-4/sample -> ~3 tail samples
#define SCAP (CAP * (CAP + 1) / 2) // 2211

// ---------------------------------------------------------------------------
// Kernel 1: cov = A * A^T in fp64 (exact).
// ---------------------------------------------------------------------------
__global__ __launch_bounds__(256) void build_cov_kernel(
    const float* __restrict__ log_diag,
    const float* __restrict__ lower_tri,
    double* __restrict__ cov)
{
    __shared__ double sLow[NTRIL];
    __shared__ double sDiag[DD];
    for (int t = threadIdx.x; t < NTRIL; t += blockDim.x)
        sLow[t] = (double)lower_tri[t];
    for (int t = threadIdx.x; t < DD; t += blockDim.x)
        sDiag[t] = exp((double)log_diag[t]);
    __syncthreads();

    int idx = blockIdx.x * blockDim.x + threadIdx.x;
    if (idx >= DD * DD) return;
    int i = idx / DD;
    int j = idx % DD;
    int mn = (i < j) ? i : j;
    int bi = i * (i - 1) / 2;
    int bj = j * (j - 1) / 2;
    double acc = 0.0;
    for (int t = 0; t < mn; ++t)
        acc += sLow[bi + t] * sLow[bj + t];
    double ai = (mn < i) ? sLow[bi + mn] : sDiag[i];
    double aj = (mn < j) ? sLow[bj + mn] : sDiag[j];
    cov[idx] = acc + ai * aj;
}

// ---------------------------------------------------------------------------
// Kernel 2a: main path, kk <= CAP. One wave per sample.
// Fused pivot-column production: while updating row i at pivot p, the lane
// writes the freshly-updated S[i][p+1] into the NEXT pivot's column buffer.
// -> one barrier per pivot (was 2) and no separate column-stage pass.
// Values are bit-identical to the staged version (same fma sequence).
// ---------------------------------------------------------------------------
__global__ __launch_bounds__(64) void nll_kernel_small(
    const float* __restrict__ x,
    const int*   __restrict__ mask,
    const float* __restrict__ mu,
    const double* __restrict__ cov,
    float* __restrict__ out)
{
    __shared__ double S[SCAP];      // 17688 B packed lower (kk <= 66)
    __shared__ double colA[CAP];
    __shared__ double colB[CAP];
    __shared__ double rz[CAP];
    __shared__ int obs[DD];

    const int b = blockIdx.x;
    const int lane = threadIdx.x;

    // ---- compact observed indices via ballot prefix ----
    int i0 = lane;
    int i1 = lane + 64;
    int m0 = (mask[b * DD + i0] != 0);
    int m1 = (i1 < DD) ? (mask[b * DD + i1] != 0) : 0;
    unsigned long long b0 = __ballot(m0);
    unsigned long long bb1 = __ballot(m1);
    unsigned long long lowmask = (1ull << lane) - 1ull;
    int k0 = __popcll(b0);
    if (m0) obs[__popcll(b0 & lowmask)] = i0;
    if (m1) obs[k0 + __popcll(bb1 & lowmask)] = i1;
    const int kk = k0 + __popcll(bb1);
    if (kk > CAP) return;           // block-uniform -> barrier-safe
    __syncthreads();

    // ---- residuals (f32 subtract, then widen) ----
    for (int i = lane; i < kk; i += 64) {
        int g = obs[i];
        float rf = x[b * DD + g] - mu[g];
        rz[i] = (double)rf;
    }

    // ---- gather packed lower submatrix (f64), jitter on diagonal;
    //      column 0 doubles as the first pivot column ----
    int T = kk * (kk + 1) / 2;
    for (int t = lane; t < T; t += 64) {
        int i = (int)((sqrt(8.0 * (double)t + 1.0) - 1.0) * 0.5);
        while ((i + 1) * (i + 2) / 2 <= t) ++i;
        while (i * (i + 1) / 2 > t) --i;
        int j = t - i * (i + 1) / 2;
        double v = cov[obs[i] * DD + obs[j]];
        if (i == j) v += JITTER;
        S[t] = v;
        if (j == 0) colA[i] = v;
    }
    __syncthreads();

    // ---- f64 LDL^T, augmented with rz; fused next-column production ----
    double* ca = colA;
    double* cb = colB;
    for (int p = 0; p < kk - 1; ++p) {
        double inv = 1.0 / ca[p];
        double rzp = rz[p];
        for (int i = p + 1 + lane; i < kk; i += 64) {
            double* Srow = S + i * (i + 1) / 2;
            double ai = ca[i] * inv;
            // peeled l = p+1: produces next pivot column entry
            double nv = Srow[p + 1] - ai * ca[p + 1];
            Srow[p + 1] = nv;
            cb[i] = nv;
            #pragma unroll 4
            for (int l = p + 2; l <= i; ++l)
                Srow[l] -= ai * ca[l];
            rz[i] -= ai * rzp;
        }
        __syncthreads();
        double* tmp = ca; ca = cb; cb = tmp;
    }

    // ---- reductions: quad = sum y^2/d, logdet = sum log d ----
    double q = 0.0, ld = 0.0;
    for (int j = lane; j < kk; j += 64) {
        double dj = S[j * (j + 1) / 2 + j];
        ld += log(dj);
        double zj = rz[j];
        q += zj * zj / dj;
    }
    for (int off = 32; off; off >>= 1) {
        q  += __shfl_down(q, off, 64);
        ld += __shfl_down(ld, off, 64);
    }
    if (lane == 0)
        out[b] = (float)(0.5 * (q + ld + (double)kk * LOG_2PI));
}

// ---------------------------------------------------------------------------
// Kernel 2b: fallback, kk > CAP (~3 samples expected). R9's verified
// structure, bit-identical math.
// ---------------------------------------------------------------------------
__global__ __launch_bounds__(64) void nll_kernel_big(
    const float* __restrict__ x,
    const int*   __restrict__ mask,
    const float* __restrict__ mu,
    const double* __restrict__ cov,
    float* __restrict__ out)
{
    __shared__ double S[DD * (DD + 1) / 2];
    __shared__ double rz[DD];
    __shared__ int obs[DD];

    const int b = blockIdx.x;
    const int lane = threadIdx.x;

    int i0 = lane;
    int i1 = lane + 64;
    int m0 = (mask[b * DD + i0] != 0);
    int m1 = (i1 < DD) ? (mask[b * DD + i1] != 0) : 0;
    unsigned long long b0 = __ballot(m0);
    unsigned long long bb1 = __ballot(m1);
    unsigned long long lowmask = (1ull << lane) - 1ull;
    int k0 = __popcll(b0);
    if (m0) obs[__popcll(b0 & lowmask)] = i0;
    if (m1) obs[k0 + __popcll(bb1 & lowmask)] = i1;
    const int kk = k0 + __popcll(bb1);
    if (kk <= CAP) return;          // main kernel handled it
    __syncthreads();

    for (int i = lane; i < kk; i += 64) {
        int g = obs[i];
        float rf = x[b * DD + g] - mu[g];
        rz[i] = (double)rf;
    }

    int T = kk * (kk + 1) / 2;
    for (int t = lane; t < T; t += 64) {
        int i = (int)((sqrt(8.0 * (double)t + 1.0) - 1.0) * 0.5);
        while ((i + 1) * (i + 2) / 2 <= t) ++i;
        while (i * (i + 1) / 2 > t) --i;
        int j = t - i * (i + 1) / 2;
        double v = cov[obs[i] * DD + obs[j]];
        if (i == j) v += JITTER;
        S[t] = v;
    }
    __syncthreads();

    for (int j = 0; j < kk; ++j) {
        double dj  = S[j * (j + 1) / 2 + j];
        double inv = 1.0 / dj;
        double rj  = rz[j];
        for (int i = j + 1 + lane; i < kk; i += 64) {
            int base = i * (i + 1) / 2;
            double a = S[base + j] * inv;
            int bl = (j + 1) * (j + 2) / 2;
            for (int l = j + 1; l <= i; ++l) {
                S[base + l] -= a * S[bl + j];
                bl += l + 1;
            }
            rz[i] -= a * rj;
        }
        __syncthreads();
    }

    double q = 0.0, ld = 0.0;
    for (int j = lane; j < kk; j += 64) {
        double dj = S[j * (j + 1) / 2 + j];
        ld += log(dj);
        double zj = rz[j];
        q += zj * zj / dj;
    }
    for (int off = 32; off; off >>= 1) {
        q  += __shfl_down(q, off, 64);
        ld += __shfl_down(ld, off, 64);
    }
    if (lane == 0)
        out[b] = (float)(0.5 * (q + ld + (double)kk * LOG_2PI));
}

// ---------------------------------------------------------------------------
extern "C" void kernel_launch(void* const* d_in, const int* in_sizes, int n_in,
                              void* d_out, int out_size, void* d_ws, size_t ws_size,
                              hipStream_t stream)
{
    const float* x         = (const float*)d_in[0];
    const int*   mask      = (const int*)d_in[1];
    const float* mu        = (const float*)d_in[2];
    const float* log_diag  = (const float*)d_in[3];
    const float* lower_tri = (const float*)d_in[4];
    float* out = (float*)d_out;

    double* cov = (double*)d_ws;   // 80 KB scratch

    const int Bn = in_sizes[0] / DD;

    build_cov_kernel<<<(DD * DD + 255) / 256, 256, 0, stream>>>(log_diag, lower_tri, cov);
    nll_kernel_small<<<Bn, 64, 0, stream>>>(x, mask, mu, cov, out);
    nll_kernel_big<<<Bn, 64, 0, stream>>>(x, mask, mu, cov, out);
}

// Round 12
// 391.789 us; speedup vs baseline: 1.2239x; 1.2239x over previous
//
#include <hip/hip_runtime.h>
#include <math.h>

#define DD 100
#define NTRIL 4950                 // D*(D-1)/2
#define NPACK (DD * (DD + 1) / 2)  // 5050
#define LOG_2PI 1.8378770664093453
#define JITTER 5.5e-8              // calibrated vs np twin (R7-R9 probes)
#define RCAP 64                    // register path: one row per lane
#define SPACK (RCAP * (RCAP + 1) / 2)  // 2080

// ---------------------------------------------------------------------------
// Kernel 1: cov = A * A^T in fp64 (exact).
// ---------------------------------------------------------------------------
__global__ __launch_bounds__(256) void build_cov_kernel(
    const float* __restrict__ log_diag,
    const float* __restrict__ lower_tri,
    double* __restrict__ cov)
{
    __shared__ double sLow[NTRIL];
    __shared__ double sDiag[DD];
    for (int t = threadIdx.x; t < NTRIL; t += blockDim.x)
        sLow[t] = (double)lower_tri[t];
    for (int t = threadIdx.x; t < DD; t += blockDim.x)
        sDiag[t] = exp((double)log_diag[t]);
    __syncthreads();

    int idx = blockIdx.x * blockDim.x + threadIdx.x;
    if (idx >= DD * DD) return;
    int i = idx / DD;
    int j = idx % DD;
    int mn = (i < j) ? i : j;
    int bi = i * (i - 1) / 2;
    int bj = j * (j - 1) / 2;
    double acc = 0.0;
    for (int t = 0; t < mn; ++t)
        acc += sLow[bi + t] * sLow[bj + t];
    double ai = (mn < i) ? sLow[bi + mn] : sDiag[i];
    double aj = (mn < j) ? sLow[bj + mn] : sDiag[j];
    cov[idx] = acc + ai * aj;
}

// ---------------------------------------------------------------------------
// Kernel 2a: register-resident LDL^T, kk <= 64. One wave per sample.
// Lane i owns row i of the compacted matrix in 64 f64 registers with the
// shift-down invariant v[l] = S[i][t+l] at pivot t. Pivot column broadcast
// via __shfl of the saved v[0] (c0). No barriers, no LDS in the hot loop.
// Inner loop fully unrolled with static indices; uniform guard l < kk-t.
// Identical fma sequence to the LDS versions -> same f64 result.
// ---------------------------------------------------------------------------
__global__ __launch_bounds__(64, 2) void nll_kernel_reg(
    const float* __restrict__ x,
    const int*   __restrict__ mask,
    const float* __restrict__ mu,
    const double* __restrict__ cov,
    float* __restrict__ out)
{
    __shared__ double S[SPACK];   // 16640 B staging triangle (kk <= 64)
    __shared__ int obs[DD];

    const int b = blockIdx.x;
    const int lane = threadIdx.x;

    // ---- compact observed indices via ballot prefix ----
    int i1 = lane + 64;
    int m0 = (mask[b * DD + lane] != 0);
    int m1 = (i1 < DD) ? (mask[b * DD + i1] != 0) : 0;
    unsigned long long b0 = __ballot(m0);
    unsigned long long bb1 = __ballot(m1);
    unsigned long long lowmask = (1ull << lane) - 1ull;
    int k0 = __popcll(b0);
    if (m0) obs[__popcll(b0 & lowmask)] = lane;
    if (m1) obs[k0 + __popcll(bb1 & lowmask)] = i1;
    const int kk = k0 + __popcll(bb1);
    if (lane >= kk) obs[lane] = 0;     // park lanes >= kk (slots <64 only)
    __syncthreads();
    if (kk > RCAP) return;             // fallback kernel handles (uniform)

    // ---- gather packed lower triangle into LDS (coalesced rows), jitter ----
    const int T = kk * (kk + 1) / 2;
    for (int t = lane; t < T; t += 64) {
        int i = (int)((sqrt(8.0 * (double)t + 1.0) - 1.0) * 0.5);
        while ((i + 1) * (i + 2) / 2 <= t) ++i;
        while (i * (i + 1) / 2 > t) --i;
        int j = t - i * (i + 1) / 2;
        double val = cov[obs[i] * DD + obs[j]];
        if (i == j) val += JITTER;
        S[t] = val;
    }
    __syncthreads();

    // ---- load my row into registers (unguarded: max index 2079 < SPACK) ----
    double v[RCAP];
    {
        const int base = lane * (lane + 1) / 2;
        #pragma unroll
        for (int l = 0; l < RCAP; ++l)
            v[l] = S[base + l];        // l > lane -> garbage, provably dead
    }

    // ---- residual (f32 subtract as np, then widen) ----
    const int gi = obs[lane];
    double rzv = (double)(x[b * DD + gi] - mu[gi]);
    double dcap = 1.0, ycap = 0.0;     // lanes >= kk contribute log(1)=0, 0

    // ---- wave-synchronous LDL^T with shift-down; zero barriers ----
    for (int t = 0; t < kk; ++t) {
        double c0 = v[0];              // my pivot-column entry S[i][t]
        double dp  = __shfl(c0, t);    // d_t from lane t
        double rzp = __shfl(rzv, t);   // y_t from lane t
        if (lane == t) { dcap = c0; ycap = rzv; }
        double inv = 1.0 / dp;
        double ai = c0 * inv;          // l_it (garbage for lanes <= t: dead)
        rzv = fma(-ai, rzp, rzv);
        #pragma unroll
        for (int l = 1; l < RCAP; ++l) {
            if (l < kk - t) {          // uniform guard, keeps unroll static
                double cl = __shfl(c0, t + l);   // S[t+l][t]
                v[l - 1] = fma(-ai, cl, v[l]);   // update + shift
            }
        }
    }

    // ---- reductions: quad = sum y^2/d, logdet = sum log d ----
    double q  = ycap * ycap / dcap;
    double ld = log(dcap);
    for (int off = 32; off; off >>= 1) {
        q  += __shfl_down(q, off);
        ld += __shfl_down(ld, off);
    }
    if (lane == 0)
        out[b] = (float)(0.5 * (q + ld + (double)kk * LOG_2PI));
}

// ---------------------------------------------------------------------------
// Kernel 2b: fallback, kk >= 65 (~8 samples expected). 128 threads so every
// thread owns <= 1 row: single-pass stage + single-pass update per pivot.
// ---------------------------------------------------------------------------
__global__ __launch_bounds__(128) void nll_kernel_big(
    const float* __restrict__ x,
    const int*   __restrict__ mask,
    const float* __restrict__ mu,
    const double* __restrict__ cov,
    float* __restrict__ out)
{
    __shared__ double S[NPACK];    // 40400 B
    __shared__ double col[DD];
    __shared__ double rz[DD];
    __shared__ int obs[DD];
    __shared__ int kk_sh;
    __shared__ double pq[2], pl[2];

    const int b = blockIdx.x;
    const int tid = threadIdx.x;
    const int lane = tid & 63;
    const int wv = tid >> 6;

    if (wv == 0) {
        int i1 = lane + 64;
        int m0 = (mask[b * DD + lane] != 0);
        int m1 = (i1 < DD) ? (mask[b * DD + i1] != 0) : 0;
        unsigned long long b0 = __ballot(m0);
        unsigned long long bb1 = __ballot(m1);
        unsigned long long lowmask = (1ull << lane) - 1ull;
        int k0 = __popcll(b0);
        if (m0) obs[__popcll(b0 & lowmask)] = lane;
        if (m1) obs[k0 + __popcll(bb1 & lowmask)] = i1;
        if (lane == 0) kk_sh = k0 + __popcll(bb1);
    }
    __syncthreads();
    const int kk = kk_sh;
    if (kk <= RCAP) return;        // register kernel handled it (uniform)

    // residuals (single pass, 128 threads cover kk <= 100)
    if (tid < kk) {
        int g = obs[tid];
        rz[tid] = (double)(x[b * DD + g] - mu[g]);
    }

    // gather packed lower triangle, jitter on diagonal
    int T = kk * (kk + 1) / 2;
    for (int t = tid; t < T; t += 128) {
        int i = (int)((sqrt(8.0 * (double)t + 1.0) - 1.0) * 0.5);
        while ((i + 1) * (i + 2) / 2 <= t) ++i;
        while (i * (i + 1) / 2 > t) --i;
        int j = t - i * (i + 1) / 2;
        double val = cov[obs[i] * DD + obs[j]];
        if (i == j) val += JITTER;
        S[t] = val;
    }
    __syncthreads();

    // staged-column LDL^T, one row per thread
    for (int p = 0; p < kk; ++p) {
        int l = p + tid;
        if (l < kk) col[l] = S[l * (l + 1) / 2 + p];
        __syncthreads();
        double inv = 1.0 / col[p];
        double rzp = rz[p];
        int i = p + 1 + tid;
        if (i < kk) {
            double* Srow = S + i * (i + 1) / 2;
            double ai = col[i] * inv;
            #pragma unroll 4
            for (int t2 = p + 1; t2 <= i; ++t2)
                Srow[t2] -= ai * col[t2];
            rz[i] -= ai * rzp;
        }
        __syncthreads();
    }

    // reductions
    double q = 0.0, ld = 0.0;
    if (tid < kk) {
        double dj = S[tid * (tid + 1) / 2 + tid];
        ld = log(dj);
        double zj = rz[tid];
        q = zj * zj / dj;
    }
    for (int off = 32; off; off >>= 1) {
        q  += __shfl_down(q, off);
        ld += __shfl_down(ld, off);
    }
    if (lane == 0) { pq[wv] = q; pl[wv] = ld; }
    __syncthreads();
    if (tid == 0)
        out[b] = (float)(0.5 * (pq[0] + pq[1] + pl[0] + pl[1]
                                + (double)kk * LOG_2PI));
}

// ---------------------------------------------------------------------------
extern "C" void kernel_launch(void* const* d_in, const int* in_sizes, int n_in,
                              void* d_out, int out_size, void* d_ws, size_t ws_size,
                              hipStream_t stream)
{
    const float* x         = (const float*)d_in[0];
    const int*   mask      = (const int*)d_in[1];
    const float* mu        = (const float*)d_in[2];
    const float* log_diag  = (const float*)d_in[3];
    const float* lower_tri = (const float*)d_in[4];
    float* out = (float*)d_out;

    double* cov = (double*)d_ws;   // 80 KB scratch

    const int Bn = in_sizes[0] / DD;

    build_cov_kernel<<<(DD * DD + 255) / 256, 256, 0, stream>>>(log_diag, lower_tri, cov);
    nll_kernel_reg<<<Bn, 64, 0, stream>>>(x, mask, mu, cov, out);
    nll_kernel_big<<<Bn, 128, 0, stream>>>(x, mask, mu, cov, out);
}

// Round 13
// 260.054 us; speedup vs baseline: 1.8439x; 1.5066x over previous
//
#include <hip/hip_runtime.h>
#include <math.h>

#define DD 100
#define NTRIL 4950                 // D*(D-1)/2
#define NPACK (DD * (DD + 1) / 2)  // 5050
#define LOG_2PI 1.8378770664093453
#define JITTER 5.5e-8              // calibrated vs np twin (R7-R9 probes)
#define RCAP 64

// ---------------------------------------------------------------------------
// Kernel 1: cov = A * A^T in fp64 (exact).
// ---------------------------------------------------------------------------
__global__ __launch_bounds__(256) void build_cov_kernel(
    const float* __restrict__ log_diag,
    const float* __restrict__ lower_tri,
    double* __restrict__ cov)
{
    __shared__ double sLow[NTRIL];
    __shared__ double sDiag[DD];
    for (int t = threadIdx.x; t < NTRIL; t += blockDim.x)
        sLow[t] = (double)lower_tri[t];
    for (int t = threadIdx.x; t < DD; t += blockDim.x)
        sDiag[t] = exp((double)log_diag[t]);
    __syncthreads();

    int idx = blockIdx.x * blockDim.x + threadIdx.x;
    if (idx >= DD * DD) return;
    int i = idx / DD;
    int j = idx % DD;
    int mn = (i < j) ? i : j;
    int bi = i * (i - 1) / 2;
    int bj = j * (j - 1) / 2;
    double acc = 0.0;
    for (int t = 0; t < mn; ++t)
        acc += sLow[bi + t] * sLow[bj + t];
    double ai = (mn < i) ? sLow[bi + mn] : sDiag[i];
    double aj = (mn < j) ? sLow[bj + mn] : sDiag[j];
    cov[idx] = acc + ai * aj;
}

// ---------------------------------------------------------------------------
// Kernel 2a: 2D register-tiled LDL^T, kk <= 64, one wave per sample.
// lane = 8*lc + lr. Lane owns T[j][m] = S[8(p+j)+lr][8(p+m)+lc] (p = panel,
// both rows and cols shift one slot per panel -> ALL register indices
// static). Per pivot: the 8 owner lanes (lc==tt) publish T[j][0] to LDS
// colbuf; everyone reads 8 a-values + 8 c-values and does <=64 in-register
// FMAs. ~8x fewer LDS-pipe ops per FMA than any 1D scheme.
// Dead slots only ever hold finite stale data and are never read live.
// ---------------------------------------------------------------------------
__global__ __launch_bounds__(64, 2) void nll_kernel_tile(
    const float* __restrict__ x,
    const int*   __restrict__ mask,
    const float* __restrict__ mu,
    const double* __restrict__ cov,
    float* __restrict__ out)
{
    __shared__ double colbuf[8][RCAP];   // [tt][local row]  4 KB
    __shared__ double dbuf[RCAP];
    __shared__ double ybuf[RCAP];
    __shared__ int obs[RCAP];

    const int b = blockIdx.x;
    const int lane = threadIdx.x;
    const int lr = lane & 7;
    const int lc = lane >> 3;

    // ---- compact observed indices via ballot prefix ----
    int i1 = lane + 64;
    int m0 = (mask[b * DD + lane] != 0);
    int m1v = (i1 < DD) ? (mask[b * DD + i1] != 0) : 0;
    unsigned long long b0 = __ballot(m0);
    unsigned long long bb1 = __ballot(m1v);
    unsigned long long lowmask = (1ull << lane) - 1ull;
    int k0 = __popcll(b0);
    int pos0 = __popcll(b0 & lowmask);
    int pos1 = k0 + __popcll(bb1 & lowmask);
    const int kk = k0 + __popcll(bb1);
    if (m0 && pos0 < RCAP) obs[pos0] = lane;
    if (m1v && pos1 < RCAP) obs[pos1] = i1;
    if (lane >= kk && lane < RCAP) obs[lane] = 0;  // park
    __syncthreads();
    if (kk > RCAP) return;             // uniform -> barrier-safe; fallback handles

    // ---- gather index vectors (static reg arrays) ----
    int rows[8], cols[8];
    #pragma unroll
    for (int j = 0; j < 8; ++j) rows[j] = obs[8 * j + lr];
    #pragma unroll
    for (int m = 0; m < 8; ++m) cols[m] = obs[8 * m + lc];

    // ---- direct tile load from cov (L2-resident, 80 KB) ----
    double T[8][8];
    #pragma unroll
    for (int j = 0; j < 8; ++j) {
        const int gr = 8 * j + lr;
        #pragma unroll
        for (int m = 0; m < 8; ++m) {
            const int gc = 8 * m + lc;
            double v = 0.0;
            if (gr < kk && gc <= gr) {
                v = cov[rows[j] * DD + cols[m]];
                if (gr == gc) v += JITTER;
            }
            T[j][m] = v;
        }
    }

    // ---- residuals, replicated across lc (f32 subtract as np, widened) ----
    double rz[8];
    #pragma unroll
    for (int j = 0; j < 8; ++j) {
        const int gr = 8 * j + lr;
        double v = 0.0;
        if (gr < kk) {
            int g = rows[j];
            v = (double)(x[b * DD + g] - mu[g]);
        }
        rz[j] = v;
    }

    // ---- panel loop; 8 pivots per panel, fully unrolled inside ----
    const int npan = (kk + 7) >> 3;
    for (int p = 0; p < npan; ++p) {
        const int base = 8 * p;
        const int rem = kk - base;               // pivots left (>0)
        const int jmax = (rem + 7) >> 3;         // live slots (1..8), uniform

        #pragma unroll
        for (int tt = 0; tt < 8; ++tt) {
            if (tt < rem) {
                const int t = base + tt;
                // (1) owners publish current pivot column (local row idx)
                if (lc == tt) {
                    #pragma unroll
                    for (int j = 0; j < 8; ++j)
                        if (j < jmax) colbuf[tt][8 * j + lr] = T[j][0];
                }
                __syncthreads();
                // (2) pivot scalars
                double d   = colbuf[tt][tt];      // uniform read
                double inv = 1.0 / d;
                double rzt = __shfl(rz[0], tt);   // lane tt holds row t's rz
                if (lane == 0) { dbuf[t] = d; ybuf[t] = rzt; }
                // (3) a-rows and c-cols
                double ar[8], cc[8];
                #pragma unroll
                for (int j = 0; j < 8; ++j)
                    ar[j] = (j < jmax) ? colbuf[tt][8 * j + lr] * inv : 0.0;
                #pragma unroll
                for (int m = 0; m < 8; ++m)
                    cc[m] = (m < jmax) ? colbuf[tt][8 * m + lc] : 0.0;
                // (4) rank-1 update of live slots (dead slots harmless)
                #pragma unroll
                for (int j = 0; j < 8; ++j) {
                    if (j < jmax) {
                        #pragma unroll
                        for (int m = 0; m < 8; ++m)
                            if (m < jmax)
                                T[j][m] = fma(-ar[j], cc[m], T[j][m]);
                        rz[j] = fma(-ar[j], rzt, rz[j]);
                    }
                }
            }
        }
        // ---- double panel shift: rows AND cols down one slot (static) ----
        #pragma unroll
        for (int j = 0; j < 7; ++j) {
            #pragma unroll
            for (int m = 0; m < 7; ++m)
                T[j][m] = T[j + 1][m + 1];
            rz[j] = rz[j + 1];
        }
    }

    // ---- reductions: quad = sum y^2/d, logdet = sum log d ----
    __syncthreads();
    double q = 0.0, ld = 0.0;
    if (lane < kk) {
        double d = dbuf[lane];
        double y = ybuf[lane];
        q  = y * y / d;
        ld = log(d);
    }
    for (int off = 32; off; off >>= 1) {
        q  += __shfl_down(q, off);
        ld += __shfl_down(ld, off);
    }
    if (lane == 0)
        out[b] = (float)(0.5 * (q + ld + (double)kk * LOG_2PI));
}

// ---------------------------------------------------------------------------
// Kernel 2b: fallback, kk >= 65 (~8 samples expected). 128 threads, staged
// column, one row per thread. Verified in R12.
// ---------------------------------------------------------------------------
__global__ __launch_bounds__(128) void nll_kernel_big(
    const float* __restrict__ x,
    const int*   __restrict__ mask,
    const float* __restrict__ mu,
    const double* __restrict__ cov,
    float* __restrict__ out)
{
    __shared__ double S[NPACK];    // 40400 B
    __shared__ double col[DD];
    __shared__ double rz[DD];
    __shared__ int obs[DD];
    __shared__ int kk_sh;
    __shared__ double pq[2], pl[2];

    const int b = blockIdx.x;
    const int tid = threadIdx.x;
    const int lane = tid & 63;
    const int wv = tid >> 6;

    if (wv == 0) {
        int i1 = lane + 64;
        int m0 = (mask[b * DD + lane] != 0);
        int m1 = (i1 < DD) ? (mask[b * DD + i1] != 0) : 0;
        unsigned long long b0 = __ballot(m0);
        unsigned long long bb1 = __ballot(m1);
        unsigned long long lowmask = (1ull << lane) - 1ull;
        int k0 = __popcll(b0);
        if (m0) obs[__popcll(b0 & lowmask)] = lane;
        if (m1) obs[k0 + __popcll(bb1 & lowmask)] = i1;
        if (lane == 0) kk_sh = k0 + __popcll(bb1);
    }
    __syncthreads();
    const int kk = kk_sh;
    if (kk <= RCAP) return;        // tile kernel handled it (uniform)

    if (tid < kk) {
        int g = obs[tid];
        rz[tid] = (double)(x[b * DD + g] - mu[g]);
    }

    int T = kk * (kk + 1) / 2;
    for (int t = tid; t < T; t += 128) {
        int i = (int)((sqrt(8.0 * (double)t + 1.0) - 1.0) * 0.5);
        while ((i + 1) * (i + 2) / 2 <= t) ++i;
        while (i * (i + 1) / 2 > t) --i;
        int j = t - i * (i + 1) / 2;
        double val = cov[obs[i] * DD + obs[j]];
        if (i == j) val += JITTER;
        S[t] = val;
    }
    __syncthreads();

    for (int p = 0; p < kk; ++p) {
        int l = p + tid;
        if (l < kk) col[l] = S[l * (l + 1) / 2 + p];
        __syncthreads();
        double inv = 1.0 / col[p];
        double rzp = rz[p];
        int i = p + 1 + tid;
        if (i < kk) {
            double* Srow = S + i * (i + 1) / 2;
            double ai = col[i] * inv;
            #pragma unroll 4
            for (int t2 = p + 1; t2 <= i; ++t2)
                Srow[t2] -= ai * col[t2];
            rz[i] -= ai * rzp;
        }
        __syncthreads();
    }

    double q = 0.0, ld = 0.0;
    if (tid < kk) {
        double dj = S[tid * (tid + 1) / 2 + tid];
        ld = log(dj);
        double zj = rz[tid];
        q = zj * zj / dj;
    }
    for (int off = 32; off; off >>= 1) {
        q  += __shfl_down(q, off);
        ld += __shfl_down(ld, off);
    }
    if (lane == 0) { pq[wv] = q; pl[wv] = ld; }
    __syncthreads();
    if (tid == 0)
        out[b] = (float)(0.5 * (pq[0] + pq[1] + pl[0] + pl[1]
                                + (double)kk * LOG_2PI));
}

// ---------------------------------------------------------------------------
extern "C" void kernel_launch(void* const* d_in, const int* in_sizes, int n_in,
                              void* d_out, int out_size, void* d_ws, size_t ws_size,
                              hipStream_t stream)
{
    const float* x         = (const float*)d_in[0];
    const int*   mask      = (const int*)d_in[1];
    const float* mu        = (const float*)d_in[2];
    const float* log_diag  = (const float*)d_in[3];
    const float* lower_tri = (const float*)d_in[4];
    float* out = (float*)d_out;

    double* cov = (double*)d_ws;   // 80 KB scratch

    const int Bn = in_sizes[0] / DD;

    build_cov_kernel<<<(DD * DD + 255) / 256, 256, 0, stream>>>(log_diag, lower_tri, cov);
    nll_kernel_tile<<<Bn, 64, 0, stream>>>(x, mask, mu, cov, out);
    nll_kernel_big<<<Bn, 128, 0, stream>>>(x, mask, mu, cov, out);
}

// Round 14
// 233.321 us; speedup vs baseline: 2.0551x; 1.1146x over previous
//
#include <hip/hip_runtime.h>
#include <math.h>

#define DD 100
#define NTRIL 4950                 // D*(D-1)/2
#define NPACK (DD * (DD + 1) / 2)  // 5050
#define LOG_2PI 1.8378770664093453
#define JITTER 5.5e-8              // calibrated vs np twin (R7-R9 probes)
#define RCAP 64

// ---------------------------------------------------------------------------
// Kernel 1: cov = A * A^T in fp64 (exact).
// ---------------------------------------------------------------------------
__global__ __launch_bounds__(256) void build_cov_kernel(
    const float* __restrict__ log_diag,
    const float* __restrict__ lower_tri,
    double* __restrict__ cov)
{
    __shared__ double sLow[NTRIL];
    __shared__ double sDiag[DD];
    for (int t = threadIdx.x; t < NTRIL; t += blockDim.x)
        sLow[t] = (double)lower_tri[t];
    for (int t = threadIdx.x; t < DD; t += blockDim.x)
        sDiag[t] = exp((double)log_diag[t]);
    __syncthreads();

    int idx = blockIdx.x * blockDim.x + threadIdx.x;
    if (idx >= DD * DD) return;
    int i = idx / DD;
    int j = idx % DD;
    int mn = (i < j) ? i : j;
    int bi = i * (i - 1) / 2;
    int bj = j * (j - 1) / 2;
    double acc = 0.0;
    for (int t = 0; t < mn; ++t)
        acc += sLow[bi + t] * sLow[bj + t];
    double ai = (mn < i) ? sLow[bi + mn] : sDiag[i];
    double aj = (mn < j) ? sLow[bj + mn] : sDiag[j];
    cov[idx] = acc + ai * aj;
}

// ---------------------------------------------------------------------------
// Kernel 2a: 2D register-tiled LDL^T, kk <= 64, one wave per sample.
// Pivot column broadcast by __shfl from the owner lanes' T[j][0] registers:
// zero barriers, zero LDS traffic in the hot loop (bpermute only).
// q accumulated on-the-fly (all lanes, broadcast values); logdet via one
// dsave register per lane (lane t owns pivot t), single log at the end.
// Same per-element fma sequence as R13 -> same result up to f64-lsb.
// ---------------------------------------------------------------------------
__global__ __launch_bounds__(64, 2) void nll_kernel_tile(
    const float* __restrict__ x,
    const int*   __restrict__ mask,
    const float* __restrict__ mu,
    const double* __restrict__ cov,
    float* __restrict__ out)
{
    __shared__ int obs[RCAP];

    const int b = blockIdx.x;
    const int lane = threadIdx.x;
    const int lr = lane & 7;
    const int lc = lane >> 3;

    // ---- compact observed indices via ballot prefix ----
    int i1 = lane + 64;
    int m0 = (mask[b * DD + lane] != 0);
    int m1v = (i1 < DD) ? (mask[b * DD + i1] != 0) : 0;
    unsigned long long b0 = __ballot(m0);
    unsigned long long bb1 = __ballot(m1v);
    unsigned long long lowmask = (1ull << lane) - 1ull;
    int k0 = __popcll(b0);
    int pos0 = __popcll(b0 & lowmask);
    int pos1 = k0 + __popcll(bb1 & lowmask);
    const int kk = k0 + __popcll(bb1);
    if (m0 && pos0 < RCAP) obs[pos0] = lane;
    if (m1v && pos1 < RCAP) obs[pos1] = i1;
    if (lane >= kk && lane < RCAP) obs[lane] = 0;  // park
    __syncthreads();
    if (kk > RCAP) return;             // uniform; fallback kernel handles

    // ---- gather index vectors (static reg arrays) ----
    int rows[8], cols[8];
    #pragma unroll
    for (int j = 0; j < 8; ++j) rows[j] = obs[8 * j + lr];
    #pragma unroll
    for (int m = 0; m < 8; ++m) cols[m] = obs[8 * m + lc];

    // ---- direct tile load from cov (L2-resident, 80 KB) ----
    double T[8][8];
    #pragma unroll
    for (int j = 0; j < 8; ++j) {
        const int gr = 8 * j + lr;
        #pragma unroll
        for (int m = 0; m < 8; ++m) {
            const int gc = 8 * m + lc;
            double v = 0.0;
            if (gr < kk && gc <= gr) {
                v = cov[rows[j] * DD + cols[m]];
                if (gr == gc) v += JITTER;
            }
            T[j][m] = v;
        }
    }

    // ---- residuals, replicated across lc (f32 subtract as np, widened) ----
    double rz[8];
    #pragma unroll
    for (int j = 0; j < 8; ++j) {
        const int gr = 8 * j + lr;
        double v = 0.0;
        if (gr < kk) {
            int g = rows[j];
            v = (double)(x[b * DD + g] - mu[g]);
        }
        rz[j] = v;
    }

    double q_acc = 0.0;
    double dsave = 1.0;          // lane t holds d_t; others contribute log(1)=0

    // ---- panel loop; 8 pivots per panel, wave-synchronous, no barriers ----
    const int npan = (kk + 7) >> 3;
    for (int p = 0; p < npan; ++p) {
        const int rem = kk - 8 * p;
        const int jmax = (rem + 7) >> 3;         // live slots (1..8), uniform

        #pragma unroll
        for (int tt = 0; tt < 8; ++tt) {
            if (tt < rem) {
                const int t = 8 * p + tt;
                double dp  = __shfl(T[0][0], 9 * tt);   // diag owner lane
                double rzt = __shfl(rz[0], tt);          // lane tt, lc=0
                double inv = 1.0 / dp;
                if (lane == t) dsave = dp;
                q_acc = fma(rzt * inv, rzt, q_acc);      // q += rzt^2/d

                double ar[8], cc[8];
                #pragma unroll
                for (int j = 0; j < 8; ++j)
                    ar[j] = (j < jmax)
                          ? __shfl(T[j][0], 8 * tt + lr) * inv : 0.0;
                #pragma unroll
                for (int m = 0; m < 8; ++m)
                    cc[m] = (m < jmax)
                          ? __shfl(T[m][0], 8 * tt + lc) : 0.0;

                #pragma unroll
                for (int j = 0; j < 8; ++j) {
                    if (j < jmax) {
                        #pragma unroll
                        for (int m = 0; m < 8; ++m)
                            if (m < jmax)
                                T[j][m] = fma(-ar[j], cc[m], T[j][m]);
                        rz[j] = fma(-ar[j], rzt, rz[j]);
                    }
                }
            }
        }
        // ---- double panel shift: rows AND cols down one slot (static) ----
        #pragma unroll
        for (int j = 0; j < 7; ++j) {
            #pragma unroll
            for (int m = 0; m < 7; ++m)
                T[j][m] = T[j + 1][m + 1];
            rz[j] = rz[j + 1];
        }
    }

    // ---- logdet: one log per lane; q_acc already identical in all lanes ----
    double ld = log(dsave);
    for (int off = 32; off; off >>= 1)
        ld += __shfl_down(ld, off);
    if (lane == 0)
        out[b] = (float)(0.5 * (q_acc + ld + (double)kk * LOG_2PI));
}

// ---------------------------------------------------------------------------
// Kernel 2b: fallback, kk >= 65 (~8 samples). 256 threads: 2 threads per row
// splitting the column range -> half the serial chain of the 128-thread
// version. Same per-element fma -> bit-identical math.
// ---------------------------------------------------------------------------
__global__ __launch_bounds__(256) void nll_kernel_big(
    const float* __restrict__ x,
    const int*   __restrict__ mask,
    const float* __restrict__ mu,
    const double* __restrict__ cov,
    float* __restrict__ out)
{
    __shared__ double S[NPACK];    // 40400 B
    __shared__ double col[DD];
    __shared__ double rz[DD];
    __shared__ int obs[DD];
    __shared__ int kk_sh;
    __shared__ double pq[4], pl[4];

    const int b = blockIdx.x;
    const int tid = threadIdx.x;
    const int lane = tid & 63;
    const int wv = tid >> 6;

    if (wv == 0) {
        int i1 = lane + 64;
        int m0 = (mask[b * DD + lane] != 0);
        int m1 = (i1 < DD) ? (mask[b * DD + i1] != 0) : 0;
        unsigned long long b0 = __ballot(m0);
        unsigned long long bb1 = __ballot(m1);
        unsigned long long lowmask = (1ull << lane) - 1ull;
        int k0 = __popcll(b0);
        if (m0) obs[__popcll(b0 & lowmask)] = lane;
        if (m1) obs[k0 + __popcll(bb1 & lowmask)] = i1;
        if (lane == 0) kk_sh = k0 + __popcll(bb1);
    }
    __syncthreads();
    const int kk = kk_sh;
    if (kk <= RCAP) return;        // tile kernel handled it (uniform)

    if (tid < kk) {
        int g = obs[tid];
        rz[tid] = (double)(x[b * DD + g] - mu[g]);
    }

    int T = kk * (kk + 1) / 2;
    for (int t = tid; t < T; t += 256) {
        int i = (int)((sqrt(8.0 * (double)t + 1.0) - 1.0) * 0.5);
        while ((i + 1) * (i + 2) / 2 <= t) ++i;
        while (i * (i + 1) / 2 > t) --i;
        int j = t - i * (i + 1) / 2;
        double val = cov[obs[i] * DD + obs[j]];
        if (i == j) val += JITTER;
        S[t] = val;
    }
    __syncthreads();

    for (int p = 0; p < kk; ++p) {
        if (tid < kk - p) {
            int l = p + tid;
            col[l] = S[l * (l + 1) / 2 + p];
        }
        __syncthreads();
        double inv = 1.0 / col[p];
        double rzp = rz[p];
        int r = tid >> 1, half = tid & 1;
        int i = p + 1 + r;
        if (i < kk) {
            double* Srow = S + i * (i + 1) / 2;
            double ai = col[i] * inv;
            int lo = p + 1;
            int len = i - p;                 // cols p+1..i inclusive
            int mid = lo + (len >> 1);
            int from = half ? mid : lo;
            int to   = half ? (i + 1) : mid;
            #pragma unroll 4
            for (int l2 = from; l2 < to; ++l2)
                Srow[l2] -= ai * col[l2];
            if (half == 0) rz[i] -= ai * rzp;
        }
        __syncthreads();
    }

    double q = 0.0, ld = 0.0;
    if (tid < kk) {
        double dj = S[tid * (tid + 1) / 2 + tid];
        ld = log(dj);
        double zj = rz[tid];
        q = zj * zj / dj;
    }
    for (int off = 32; off; off >>= 1) {
        q  += __shfl_down(q, off);
        ld += __shfl_down(ld, off);
    }
    if (lane == 0) { pq[wv] = q; pl[wv] = ld; }
    __syncthreads();
    if (tid == 0)
        out[b] = (float)(0.5 * (pq[0] + pq[1] + pq[2] + pq[3]
                                + pl[0] + pl[1] + pl[2] + pl[3]
                                + (double)kk * LOG_2PI));
}

// ---------------------------------------------------------------------------
extern "C" void kernel_launch(void* const* d_in, const int* in_sizes, int n_in,
                              void* d_out, int out_size, void* d_ws, size_t ws_size,
                              hipStream_t stream)
{
    const float* x         = (const float*)d_in[0];
    const int*   mask      = (const int*)d_in[1];
    const float* mu        = (const float*)d_in[2];
    const float* log_diag  = (const float*)d_in[3];
    const float* lower_tri = (const float*)d_in[4];
    float* out = (float*)d_out;

    double* cov = (double*)d_ws;   // 80 KB scratch

    const int Bn = in_sizes[0] / DD;

    build_cov_kernel<<<(DD * DD + 255) / 256, 256, 0, stream>>>(log_diag, lower_tri, cov);
    nll_kernel_tile<<<Bn, 64, 0, stream>>>(x, mask, mu, cov, out);
    nll_kernel_big<<<Bn, 256, 0, stream>>>(x, mask, mu, cov, out);
}